// Round 1
// baseline (434.055 us; speedup 1.0000x reference)
//
#include <hip/hip_runtime.h>

typedef unsigned short u16;
typedef __attribute__((ext_vector_type(8))) short bf16x8;
typedef __attribute__((ext_vector_type(4))) float f32x4;

#define DEV static __device__ __forceinline__

DEV u16 f2bf(float f) {
  union { float f; unsigned u; } x; x.f = f;
  return (u16)((x.u + 0x7FFFu + ((x.u >> 16) & 1u)) >> 16);
}

#if __has_builtin(__builtin_amdgcn_global_load_lds)
DEV void gload16(const void* g, void* l) {
  __builtin_amdgcn_global_load_lds((const __attribute__((address_space(1))) void*)g,
                                   (__attribute__((address_space(3))) void*)l, 16, 0, 0);
}
#else
DEV void gload16(const void* g, void* l) { *(int4*)l = *(const int4*)g; }
#endif

// ---------------- GroupNorm stats (2-stage) ----------------
// x slab for (b,g) is contiguous: 16 ch * 16384 = 262144 floats.
__global__ __launch_bounds__(256) void gn_stats_a(const float* __restrict__ x,
                                                  float2* __restrict__ part) {
  const int bg = blockIdx.x >> 5, slice = blockIdx.x & 31;
  const float* base = x + (long)bg * 262144 + slice * 8192;
  float s = 0.f, q = 0.f;
#pragma unroll
  for (int i = 0; i < 8; ++i) {
    float4 v = *(const float4*)(base + i * 1024 + threadIdx.x * 4);
    s += v.x + v.y + v.z + v.w;
    q += v.x * v.x + v.y * v.y + v.z * v.z + v.w * v.w;
  }
#pragma unroll
  for (int o = 32; o; o >>= 1) { s += __shfl_xor(s, o); q += __shfl_xor(q, o); }
  __shared__ float2 red[4];
  if ((threadIdx.x & 63) == 0) red[threadIdx.x >> 6] = make_float2(s, q);
  __syncthreads();
  if (threadIdx.x == 0) {
    float S = 0.f, Q = 0.f;
    for (int i = 0; i < 4; ++i) { S += red[i].x; Q += red[i].y; }
    part[blockIdx.x] = make_float2(S, Q);
  }
}

__global__ void gn_stats_b(const float2* __restrict__ part, float2* __restrict__ stats) {
  float s = 0.f, q = 0.f;
  if (threadIdx.x < 32) {
    float2 p = part[blockIdx.x * 32 + threadIdx.x];
    s = p.x; q = p.y;
  }
#pragma unroll
  for (int o = 32; o; o >>= 1) { s += __shfl_xor(s, o); q += __shfl_xor(q, o); }
  if (threadIdx.x == 0) {
    const float inv = 1.f / 262144.f;
    float mean = s * inv;
    float var = q * inv - mean * mean;
    stats[blockIdx.x] = make_float2(mean, rsqrtf(var + 1e-6f));
  }
}

// Normalize + transpose [b,c,t,p] -> hn[(b*16+t)*1024+p][c] bf16
__global__ __launch_bounds__(256) void gn_apply(const float* __restrict__ x,
                                                const float* __restrict__ gamma,
                                                const float* __restrict__ beta,
                                                const float2* __restrict__ stats,
                                                u16* __restrict__ hn) {
  __shared__ u16 tile[64][65];
  const int p0 = blockIdx.x * 64, c0 = blockIdx.y * 64, bt = blockIdx.z;
  const int b = bt >> 4, t = bt & 15, tid = threadIdx.x;
  const float* xb = x + (long)b * 8388608 + t * 1024;
#pragma unroll 4
  for (int r = 0; r < 16; ++r) {
    int ci = r * 4 + (tid >> 6), pi = tid & 63;
    int c = c0 + ci;
    float2 st = stats[b * 32 + (c >> 4)];
    float v = xb[(long)c * 16384 + p0 + pi];
    v = (v - st.x) * st.y * gamma[c] + beta[c];
    tile[ci][pi] = f2bf(v);
  }
  __syncthreads();
  u16* hb = hn + ((long)bt * 1024 + p0) * 512 + c0;
#pragma unroll 4
  for (int r = 0; r < 16; ++r) {
    int pi = r * 4 + (tid >> 6), ci = tid & 63;
    hb[(long)pi * 512 + ci] = tile[ci][pi];
  }
}

// fp32 -> bf16 weight convert: 4 matrices of 512*512, concatenated dst
__global__ __launch_bounds__(256) void wconv(const float* __restrict__ w0, const float* __restrict__ w1,
                                             const float* __restrict__ w2, const float* __restrict__ w3,
                                             u16* __restrict__ dst) {
  int e = (blockIdx.x * 256 + threadIdx.x) * 4;
  const float* src = w0;
  int which = e >> 18, off = e & 262143;
  if (which == 1) src = w1; else if (which == 2) src = w2; else if (which == 3) src = w3;
  float4 v = *(const float4*)(src + off);
  ushort4 o;
  o.x = f2bf(v.x); o.y = f2bf(v.y); o.z = f2bf(v.z); o.w = f2bf(v.w);
  *(ushort4*)(dst + e) = o;
}

// v[bt][p][c] -> vT[bt][c][p]  (bf16)
__global__ __launch_bounds__(256) void transpose_pc(const u16* __restrict__ v, u16* __restrict__ vT) {
  __shared__ u16 tile[64][65];
  const int p0 = blockIdx.x * 64, c0 = blockIdx.y * 64;
  const long bt = blockIdx.z;
  const int tid = threadIdx.x;
  const u16* vb = v + bt * 524288;
#pragma unroll 4
  for (int r = 0; r < 16; ++r) {
    int pi = r * 4 + (tid >> 6), ci = tid & 63;
    tile[pi][ci] = vb[(long)(p0 + pi) * 512 + c0 + ci];
  }
  __syncthreads();
  u16* ob = vT + bt * 524288;
#pragma unroll 4
  for (int r = 0; r < 16; ++r) {
    int ci = r * 4 + (tid >> 6), pi = tid & 63;
    ob[(long)(c0 + ci) * 1024 + p0 + pi] = tile[pi][ci];
  }
}

// Row softmax over 1024 cols; reads fp32 scores, writes bf16 P in place
// (row r's bf16 row lives in the first 2KB of its 4KB fp32 row => lda 2048 u16)
__global__ __launch_bounds__(256) void softmax_rows(float* __restrict__ scores) {
  const int wave = threadIdx.x >> 6, lane = threadIdx.x & 63;
  const long row = (long)blockIdx.x * 4 + wave;
  float* srow = scores + row * 1024;
  float4 v[4];
  float m = -3.4e38f;
#pragma unroll
  for (int i = 0; i < 4; ++i) {
    v[i] = *(const float4*)(srow + i * 256 + lane * 4);
    m = fmaxf(m, fmaxf(fmaxf(v[i].x, v[i].y), fmaxf(v[i].z, v[i].w)));
  }
#pragma unroll
  for (int o = 32; o; o >>= 1) m = fmaxf(m, __shfl_xor(m, o));
  const float sc = 0.044194173824159216f;  // 1/sqrt(512)
  float e[16];
  float s = 0.f;
#pragma unroll
  for (int i = 0; i < 4; ++i) {
    e[i * 4 + 0] = __expf((v[i].x - m) * sc);
    e[i * 4 + 1] = __expf((v[i].y - m) * sc);
    e[i * 4 + 2] = __expf((v[i].z - m) * sc);
    e[i * 4 + 3] = __expf((v[i].w - m) * sc);
    s += e[i * 4] + e[i * 4 + 1] + e[i * 4 + 2] + e[i * 4 + 3];
  }
#pragma unroll
  for (int o = 32; o; o >>= 1) s += __shfl_xor(s, o);
  const float inv = 1.f / s;
  u16* prow = (u16*)scores + row * 2048;
#pragma unroll
  for (int i = 0; i < 4; ++i) {
    ushort4 o4;
    o4.x = f2bf(e[i * 4 + 0] * inv);
    o4.y = f2bf(e[i * 4 + 1] * inv);
    o4.z = f2bf(e[i * 4 + 2] * inv);
    o4.w = f2bf(e[i * 4 + 3] * inv);
    *(ushort4*)(prow + i * 256 + lane * 4) = o4;
  }
}

// ---------------- NT GEMM: C[m,n] = sum_k A[m,k]*B[n,k] (+bias[n]) ----------------
// bf16 in, fp32 or bf16 out. 128x128 tile, BK=64, 256 thr (4 waves, each 64x64).
template <bool OUT_BF16, bool HAS_BIAS>
__global__ __launch_bounds__(256) void gemm_nt(const u16* __restrict__ A, int lda, long sA,
                                               const u16* __restrict__ B, int ldb, long sB,
                                               void* __restrict__ Cv, int ldc, long sC,
                                               const float* __restrict__ bias, int K) {
  __shared__ u16 lA[128 * 64];
  __shared__ u16 lB[128 * 64];
  const int tid = threadIdx.x;
  const int wave = tid >> 6, lane = tid & 63;
  const long m0 = (long)blockIdx.x * 128;
  const long n0 = (long)blockIdx.y * 128;
  A += (long)blockIdx.z * sA;
  B += (long)blockIdx.z * sB;

  f32x4 acc[4][4] = {};

  const int wrow = (wave >> 1) * 64;
  const int wcol = (wave & 1) * 64;
  const int srow = tid >> 3;          // 0..31 (tile row per stage issue)
  const int scol = (tid & 7) * 8;     // element offset within row
  char* ldsA = (char*)lA + wave * 1024 + lane * 16;
  char* ldsB = (char*)lB + wave * 1024 + lane * 16;

  for (int k0 = 0; k0 < K; k0 += 64) {
#pragma unroll
    for (int i = 0; i < 4; ++i) {
      gload16(A + (m0 + i * 32 + srow) * lda + k0 + scol, ldsA + i * 4096);
      gload16(B + (n0 + i * 32 + srow) * ldb + k0 + scol, ldsB + i * 4096);
    }
    __syncthreads();
    const int krd = (lane >> 4) * 8;
    const int lrow = lane & 15;
#pragma unroll
    for (int kk = 0; kk < 2; ++kk) {
      bf16x8 af[4], bfr[4];
#pragma unroll
      for (int mi = 0; mi < 4; ++mi)
        af[mi] = *(const bf16x8*)&lA[(wrow + mi * 16 + lrow) * 64 + kk * 32 + krd];
#pragma unroll
      for (int ni = 0; ni < 4; ++ni)
        bfr[ni] = *(const bf16x8*)&lB[(wcol + ni * 16 + lrow) * 64 + kk * 32 + krd];
#pragma unroll
      for (int mi = 0; mi < 4; ++mi)
#pragma unroll
        for (int ni = 0; ni < 4; ++ni)
          acc[mi][ni] = __builtin_amdgcn_mfma_f32_16x16x32_bf16(af[mi], bfr[ni], acc[mi][ni], 0, 0, 0);
    }
    __syncthreads();
  }

  // C/D layout: col = lane&15, row = (lane>>4)*4 + j   [guide §3, m89-verified]
  const int lc = lane & 15, lr = (lane >> 4) * 4;
  if (OUT_BF16) {
    u16* C = (u16*)Cv + (long)blockIdx.z * sC;
#pragma unroll
    for (int mi = 0; mi < 4; ++mi)
#pragma unroll
      for (int ni = 0; ni < 4; ++ni) {
        long r = m0 + wrow + mi * 16 + lr;
        long c = n0 + wcol + ni * 16 + lc;
        float bv = HAS_BIAS ? bias[c] : 0.f;
#pragma unroll
        for (int j = 0; j < 4; ++j) C[(r + j) * ldc + c] = f2bf(acc[mi][ni][j] + bv);
      }
  } else {
    float* C = (float*)Cv + (long)blockIdx.z * sC;
#pragma unroll
    for (int mi = 0; mi < 4; ++mi)
#pragma unroll
      for (int ni = 0; ni < 4; ++ni) {
        long r = m0 + wrow + mi * 16 + lr;
        long c = n0 + wcol + ni * 16 + lc;
        float bv = HAS_BIAS ? bias[c] : 0.f;
#pragma unroll
        for (int j = 0; j < 4; ++j) C[(r + j) * ldc + c] = acc[mi][ni][j] + bv;
      }
  }
}

// projout[m][c] (+proj_b) + x -> d_out in [b,c,t,p] layout
__global__ __launch_bounds__(256) void final_write(const float* __restrict__ projout,
                                                   const float* __restrict__ proj_b,
                                                   const float* __restrict__ x,
                                                   float* __restrict__ out) {
  __shared__ float tile[64][65];
  const int p0 = blockIdx.x * 64, c0 = blockIdx.y * 64, bt = blockIdx.z;
  const int b = bt >> 4, t = bt & 15, tid = threadIdx.x;
  const float* pr = projout + ((long)bt * 1024 + p0) * 512 + c0;
#pragma unroll 4
  for (int r = 0; r < 16; ++r) {
    int pi = r * 4 + (tid >> 6), ci = tid & 63;
    tile[pi][ci] = pr[(long)pi * 512 + ci];
  }
  __syncthreads();
  const long obase = (long)b * 8388608 + t * 1024;
#pragma unroll 4
  for (int r = 0; r < 16; ++r) {
    int ci = r * 4 + (tid >> 6), pi = tid & 63;
    long idx = obase + (long)(c0 + ci) * 16384 + p0 + pi;
    out[idx] = x[idx] + proj_b[c0 + ci] + tile[pi][ci];
  }
}

extern "C" void kernel_launch(void* const* d_in, const int* in_sizes, int n_in,
                              void* d_out, int out_size, void* d_ws, size_t ws_size,
                              hipStream_t stream) {
  (void)in_sizes; (void)n_in; (void)out_size; (void)ws_size;
  const float* x      = (const float*)d_in[0];
  const float* gamma  = (const float*)d_in[1];
  const float* beta   = (const float*)d_in[2];
  const float* q_w    = (const float*)d_in[3];
  const float* q_b    = (const float*)d_in[4];
  const float* k_w    = (const float*)d_in[5];
  const float* k_b    = (const float*)d_in[6];
  const float* v_w    = (const float*)d_in[7];
  const float* v_b    = (const float*)d_in[8];
  const float* proj_w = (const float*)d_in[9];
  const float* proj_b = (const float*)d_in[10];

  // workspace layout (bytes); total need ~194 MB
  const size_t OFF_STATS = 0;            // 64*2*4
  const size_t OFF_PART  = 1024;         // 2048*2*4
  const size_t OFF_WB    = 32768;        // 4*512*512*2 = 2 MB
  const size_t OFF_HN    = 2129920;      // 32 MB (reused as vT)
  const size_t OFF_Q     = 35684352;     // 32 MB (q; later projout spans q+k = 64 MB)
  const size_t OFF_K     = 69238784;     // 32 MB
  const size_t OFF_V     = 102793216;    // 32 MB
  const size_t OFF_SC    = 136347648;    // 8 frames * 1024*1024*4 = 32 MB (scores/P, chunked)
  const size_t OFF_O     = 169902080;    // 32 MB

  char* ws = (char*)d_ws;
  float2* stats   = (float2*)(ws + OFF_STATS);
  float2* part    = (float2*)(ws + OFF_PART);
  u16*    wb      = (u16*)(ws + OFF_WB);
  u16*    wq      = wb;
  u16*    wk      = wb + 262144;
  u16*    wv      = wb + 524288;
  u16*    wp      = wb + 786432;
  u16*    hn      = (u16*)(ws + OFF_HN);
  u16*    vT      = hn;                       // reuse (hn dead after QKV GEMMs)
  u16*    qb      = (u16*)(ws + OFF_Q);
  u16*    kb      = (u16*)(ws + OFF_K);
  u16*    vb      = (u16*)(ws + OFF_V);
  float*  scores  = (float*)(ws + OFF_SC);
  u16*    ob      = (u16*)(ws + OFF_O);
  float*  projout = (float*)(ws + OFF_Q);     // overlays q+k (dead by then)

  wconv<<<1024, 256, 0, stream>>>(q_w, k_w, v_w, proj_w, wb);
  gn_stats_a<<<2048, 256, 0, stream>>>(x, part);
  gn_stats_b<<<64, 64, 0, stream>>>(part, stats);
  gn_apply<<<dim3(16, 8, 32), 256, 0, stream>>>(x, gamma, beta, stats, hn);

  // QKV: M=32768, N=512, K=512
  gemm_nt<true, true><<<dim3(256, 4, 1), 256, 0, stream>>>(hn, 512, 0, wq, 512, 0, qb, 512, 0, q_b, 512);
  gemm_nt<true, true><<<dim3(256, 4, 1), 256, 0, stream>>>(hn, 512, 0, wk, 512, 0, kb, 512, 0, k_b, 512);
  gemm_nt<true, true><<<dim3(256, 4, 1), 256, 0, stream>>>(hn, 512, 0, wv, 512, 0, vb, 512, 0, v_b, 512);

  transpose_pc<<<dim3(16, 8, 32), 256, 0, stream>>>(vb, vT);

  // attention, 8 frames per chunk
  for (int ch = 0; ch < 4; ++ch) {
    long f0 = (long)ch * 8;
    // scores = q @ k^T : M=N=1024, K=512, batched over 8 frames
    gemm_nt<false, false><<<dim3(8, 8, 8), 256, 0, stream>>>(
        qb + f0 * 524288, 512, 524288, kb + f0 * 524288, 512, 524288,
        scores, 1024, 1048576, nullptr, 512);
    softmax_rows<<<2048, 256, 0, stream>>>(scores);
    // o = P @ vT^T : M=1024, N=512, K=1024 (P rows strided 2048 u16)
    gemm_nt<true, false><<<dim3(8, 4, 8), 256, 0, stream>>>(
        (const u16*)scores, 2048, 2097152, vT + f0 * 524288, 1024, 524288,
        ob + f0 * 524288, 512, 524288, nullptr, 1024);
  }

  // proj: M=32768, N=512, K=512 -> fp32
  gemm_nt<false, false><<<dim3(256, 4, 1), 256, 0, stream>>>(ob, 512, 0, wp, 512, 0,
                                                             projout, 512, 0, nullptr, 512);
  final_write<<<dim3(16, 8, 32), 256, 0, stream>>>(projout, proj_b, x, (float*)d_out);
}

// Round 2
// 318.682 us; speedup vs baseline: 1.3620x; 1.3620x over previous
//
#include <hip/hip_runtime.h>

typedef unsigned short u16;
typedef __attribute__((ext_vector_type(8))) short bf16x8;
typedef __attribute__((ext_vector_type(4))) float f32x4;

#define DEV static __device__ __forceinline__

DEV u16 f2bf(float f) {
  union { float f; unsigned u; } x; x.f = f;
  return (u16)((x.u + 0x7FFFu + ((x.u >> 16) & 1u)) >> 16);
}
DEV float bf2f(u16 h) { union { unsigned u; float f; } x; x.u = ((unsigned)h) << 16; return x.f; }

DEV void gload16(const void* g, void* l) {
  __builtin_amdgcn_global_load_lds((const __attribute__((address_space(1))) void*)g,
                                   (__attribute__((address_space(3))) void*)l, 16, 0, 0);
}

// ---------------- GroupNorm stats (2-stage) ----------------
__global__ __launch_bounds__(256) void gn_stats_a(const float* __restrict__ x,
                                                  float2* __restrict__ part) {
  const int bg = blockIdx.x >> 5, slice = blockIdx.x & 31;
  const float* base = x + (long)bg * 262144 + slice * 8192;
  float s = 0.f, q = 0.f;
#pragma unroll
  for (int i = 0; i < 8; ++i) {
    float4 v = *(const float4*)(base + i * 1024 + threadIdx.x * 4);
    s += v.x + v.y + v.z + v.w;
    q += v.x * v.x + v.y * v.y + v.z * v.z + v.w * v.w;
  }
#pragma unroll
  for (int o = 32; o; o >>= 1) { s += __shfl_xor(s, o); q += __shfl_xor(q, o); }
  __shared__ float2 red[4];
  if ((threadIdx.x & 63) == 0) red[threadIdx.x >> 6] = make_float2(s, q);
  __syncthreads();
  if (threadIdx.x == 0) {
    float S = 0.f, Q = 0.f;
    for (int i = 0; i < 4; ++i) { S += red[i].x; Q += red[i].y; }
    part[blockIdx.x] = make_float2(S, Q);
  }
}

__global__ void gn_stats_b(const float2* __restrict__ part, float2* __restrict__ stats) {
  float s = 0.f, q = 0.f;
  if (threadIdx.x < 32) {
    float2 p = part[blockIdx.x * 32 + threadIdx.x];
    s = p.x; q = p.y;
  }
#pragma unroll
  for (int o = 32; o; o >>= 1) { s += __shfl_xor(s, o); q += __shfl_xor(q, o); }
  if (threadIdx.x == 0) {
    const float inv = 1.f / 262144.f;
    float mean = s * inv;
    float var = q * inv - mean * mean;
    stats[blockIdx.x] = make_float2(mean, rsqrtf(var + 1e-6f));
  }
}

// Normalize + transpose [b,c,t,p] -> hn[(b*16+t)*1024+p][c] bf16
__global__ __launch_bounds__(256) void gn_apply(const float* __restrict__ x,
                                                const float* __restrict__ gamma,
                                                const float* __restrict__ beta,
                                                const float2* __restrict__ stats,
                                                u16* __restrict__ hn) {
  __shared__ u16 tile[64][65];
  const int p0 = blockIdx.x * 64, c0 = blockIdx.y * 64, bt = blockIdx.z;
  const int b = bt >> 4, t = bt & 15, tid = threadIdx.x;
  const float* xb = x + (long)b * 8388608 + t * 1024;
#pragma unroll 4
  for (int r = 0; r < 16; ++r) {
    int ci = r * 4 + (tid >> 6), pi = tid & 63;
    int c = c0 + ci;
    float2 st = stats[b * 32 + (c >> 4)];
    float v = xb[(long)c * 16384 + p0 + pi];
    v = (v - st.x) * st.y * gamma[c] + beta[c];
    tile[ci][pi] = f2bf(v);
  }
  __syncthreads();
  u16* hb = hn + ((long)bt * 1024 + p0) * 512 + c0;
#pragma unroll 4
  for (int r = 0; r < 16; ++r) {
    int pi = r * 4 + (tid >> 6), ci = tid & 63;
    hb[(long)pi * 512 + ci] = tile[ci][pi];
  }
}

// fp32 -> bf16 weight convert: 4 matrices of 512*512 concatenated (q,k,v rows 0..1535, proj last)
__global__ __launch_bounds__(256) void wconv(const float* __restrict__ w0, const float* __restrict__ w1,
                                             const float* __restrict__ w2, const float* __restrict__ w3,
                                             u16* __restrict__ dst) {
  int e = (blockIdx.x * 256 + threadIdx.x) * 4;
  const float* src = w0;
  int which = e >> 18, off = e & 262143;
  if (which == 1) src = w1; else if (which == 2) src = w2; else if (which == 3) src = w3;
  float4 v = *(const float4*)(src + off);
  ushort4 o;
  o.x = f2bf(v.x); o.y = f2bf(v.y); o.z = f2bf(v.z); o.w = f2bf(v.w);
  *(ushort4*)(dst + e) = o;
}

__global__ void bcat(const float* __restrict__ qb, const float* __restrict__ kb,
                     const float* __restrict__ vb, float* __restrict__ dst) {
  int i = blockIdx.x * 256 + threadIdx.x;
  if (i < 512) dst[i] = qb[i];
  else if (i < 1024) dst[i] = kb[i - 512];
  else if (i < 1536) dst[i] = vb[i - 1024];
}

// v[bt][p][c] (row stride ldv) -> vT[bt][c][p]  (bf16)
__global__ __launch_bounds__(256) void transpose_pc(const u16* __restrict__ v, int ldv,
                                                    u16* __restrict__ vT) {
  __shared__ u16 tile[64][65];
  const int p0 = blockIdx.x * 64, c0 = blockIdx.y * 64;
  const long bt = blockIdx.z;
  const int tid = threadIdx.x;
  const u16* vb = v + bt * 1024 * (long)ldv;
#pragma unroll 4
  for (int r = 0; r < 16; ++r) {
    int pi = r * 4 + (tid >> 6), ci = tid & 63;
    tile[pi][ci] = vb[(long)(p0 + pi) * ldv + c0 + ci];
  }
  __syncthreads();
  u16* ob = vT + bt * 524288;
#pragma unroll 4
  for (int r = 0; r < 16; ++r) {
    int ci = r * 4 + (tid >> 6), pi = tid & 63;
    ob[(long)(c0 + ci) * 1024 + p0 + pi] = tile[pi][ci];
  }
}

// Row softmax over 1024 bf16 cols, in place. 4 rows/block (1 row per wave).
__global__ __launch_bounds__(256) void softmax_rows_bf16(u16* __restrict__ scores) {
  const int wave = threadIdx.x >> 6, lane = threadIdx.x & 63;
  const long row = (long)blockIdx.x * 4 + wave;
  u16* srow = scores + row * 1024;
  bf16x8 a0 = *(const bf16x8*)(srow + lane * 16);
  bf16x8 a1 = *(const bf16x8*)(srow + lane * 16 + 8);
  float v[16];
#pragma unroll
  for (int j = 0; j < 8; ++j) { v[j] = bf2f((u16)a0[j]); v[8 + j] = bf2f((u16)a1[j]); }
  float m = v[0];
#pragma unroll
  for (int j = 1; j < 16; ++j) m = fmaxf(m, v[j]);
#pragma unroll
  for (int o = 32; o; o >>= 1) m = fmaxf(m, __shfl_xor(m, o));
  const float sc = 0.044194173824159216f;  // 1/sqrt(512)
  float s = 0.f, e[16];
#pragma unroll
  for (int j = 0; j < 16; ++j) { e[j] = __expf((v[j] - m) * sc); s += e[j]; }
#pragma unroll
  for (int o = 32; o; o >>= 1) s += __shfl_xor(s, o);
  const float inv = 1.f / s;
  bf16x8 o0, o1;
#pragma unroll
  for (int j = 0; j < 8; ++j) {
    o0[j] = (short)f2bf(e[j] * inv);
    o1[j] = (short)f2bf(e[8 + j] * inv);
  }
  *(bf16x8*)(srow + lane * 16) = o0;
  *(bf16x8*)(srow + lane * 16 + 8) = o1;
}

// ---------------- NT GEMM, 256x256 tile, BK=32, depth-2 prefetch pipeline ----------------
// C[m,n] = sum_k A[m,k]*B[n,k] (+bias[n]).  8 waves (2M x 4N), wave tile 128x64.
// 3 LDS buffers (96 KB), counted vmcnt(8): tile t+2 staged while computing t.
// LDS rows are 64 B; swizzle cb ^= ((row>>1)&3)<<4 applied on the READ side and
// (inverse == same XOR) pre-applied to the per-lane GLOBAL source, dest stays linear.
template <bool OUT_BF16, bool HAS_BIAS>
__global__ __launch_bounds__(512, 2) void gemm256(
    const u16* __restrict__ A, int lda, long sA,
    const u16* __restrict__ B, int ldb, long sB,
    void* __restrict__ Cv, int ldc, long sC,
    const float* __restrict__ bias, int K) {
  __shared__ u16 sm[3 * 16384];  // buf b: A at b*16384, B at b*16384+8192 (u16 units)
  const int tid = threadIdx.x;
  const int wid = tid >> 6, lane = tid & 63;
  const int wm = wid >> 2, wn = wid & 3;
  const long m0 = (long)blockIdx.x * 256;
  const long n0 = (long)blockIdx.y * 256;
  A += (long)blockIdx.z * sA + m0 * lda;
  B += (long)blockIdx.z * sB + n0 * ldb;
  const int NT = K >> 5;

  f32x4 acc[8][4] = {};

  const int r0 = tid >> 2;          // staging row (issue 0), 0..127
  const int slot = (tid & 3) * 16;  // 16B slot within 64B row

  auto STAGE = [&](int kt, int b) {
    char* sA_ = (char*)&sm[b * 16384];
    char* sB_ = (char*)&sm[b * 16384 + 8192];
    const long kOff = (long)kt * 32;
#pragma unroll
    for (int i = 0; i < 2; ++i) {
      int row = i * 128 + r0;
      int cb = slot ^ (((row >> 1) & 3) << 4);
      gload16((const char*)(A + (long)row * lda + kOff) + cb, sA_ + i * 8192 + tid * 16);
      gload16((const char*)(B + (long)row * ldb + kOff) + cb, sB_ + i * 8192 + tid * 16);
    }
  };

  STAGE(0, 0);
  if (NT > 1) STAGE(1, 1);

  const int lrow = lane & 15;
  const int kslot = (lane >> 4) * 16;

  for (int t = 0; t < NT; ++t) {
    const int cur = t % 3;
    if (t + 2 < NT) {
      STAGE(t + 2, (t + 2) % 3);
      asm volatile("s_waitcnt vmcnt(8)" ::: "memory");
    } else if (t + 1 < NT) {
      asm volatile("s_waitcnt vmcnt(4)" ::: "memory");
    } else {
      asm volatile("s_waitcnt vmcnt(0)" ::: "memory");
    }
    __builtin_amdgcn_s_barrier();
    asm volatile("" ::: "memory");

    const char* bufA = (const char*)&sm[cur * 16384];
    const char* bufB = (const char*)&sm[cur * 16384 + 8192];
    bf16x8 af[8], bf[4];
#pragma unroll
    for (int mi = 0; mi < 8; ++mi) {
      int row = wm * 128 + mi * 16 + lrow;
      af[mi] = *(const bf16x8*)(bufA + row * 64 + (kslot ^ (((row >> 1) & 3) << 4)));
    }
#pragma unroll
    for (int ni = 0; ni < 4; ++ni) {
      int row = wn * 64 + ni * 16 + lrow;
      bf[ni] = *(const bf16x8*)(bufB + row * 64 + (kslot ^ (((row >> 1) & 3) << 4)));
    }
    __builtin_amdgcn_s_setprio(1);
#pragma unroll
    for (int mi = 0; mi < 8; ++mi)
#pragma unroll
      for (int ni = 0; ni < 4; ++ni)
        acc[mi][ni] = __builtin_amdgcn_mfma_f32_16x16x32_bf16(af[mi], bf[ni], acc[mi][ni], 0, 0, 0);
    __builtin_amdgcn_s_setprio(0);
    asm volatile("" ::: "memory");
    __builtin_amdgcn_s_barrier();
  }

  // C/D layout: col = lane&15, row = (lane>>4)*4 + j
  const int lc = lane & 15, lr = (lane >> 4) * 4;
  if (OUT_BF16) {
    u16* C = (u16*)Cv + (long)blockIdx.z * sC;
#pragma unroll
    for (int mi = 0; mi < 8; ++mi) {
      long r = m0 + wm * 128 + mi * 16 + lr;
#pragma unroll
      for (int ni = 0; ni < 4; ++ni) {
        long c = n0 + wn * 64 + ni * 16 + lc;
        float bv = HAS_BIAS ? bias[c] : 0.f;
#pragma unroll
        for (int j = 0; j < 4; ++j) C[(r + j) * ldc + c] = f2bf(acc[mi][ni][j] + bv);
      }
    }
  } else {
    float* C = (float*)Cv + (long)blockIdx.z * sC;
#pragma unroll
    for (int mi = 0; mi < 8; ++mi) {
      long r = m0 + wm * 128 + mi * 16 + lr;
#pragma unroll
      for (int ni = 0; ni < 4; ++ni) {
        long c = n0 + wn * 64 + ni * 16 + lc;
        float bv = HAS_BIAS ? bias[c] : 0.f;
#pragma unroll
        for (int j = 0; j < 4; ++j) C[(r + j) * ldc + c] = acc[mi][ni][j] + bv;
      }
    }
  }
}

// projout[m][c] (+proj_b) + x -> d_out in [b,c,t,p] layout
__global__ __launch_bounds__(256) void final_write(const float* __restrict__ projout,
                                                   const float* __restrict__ proj_b,
                                                   const float* __restrict__ x,
                                                   float* __restrict__ out) {
  __shared__ float tile[64][65];
  const int p0 = blockIdx.x * 64, c0 = blockIdx.y * 64, bt = blockIdx.z;
  const int b = bt >> 4, t = bt & 15, tid = threadIdx.x;
  const float* pr = projout + ((long)bt * 1024 + p0) * 512 + c0;
#pragma unroll 4
  for (int r = 0; r < 16; ++r) {
    int pi = r * 4 + (tid >> 6), ci = tid & 63;
    tile[pi][ci] = pr[(long)pi * 512 + ci];
  }
  __syncthreads();
  const long obase = (long)b * 8388608 + t * 1024;
#pragma unroll 4
  for (int r = 0; r < 16; ++r) {
    int ci = r * 4 + (tid >> 6), pi = tid & 63;
    long idx = obase + (long)(c0 + ci) * 16384 + p0 + pi;
    out[idx] = x[idx] + proj_b[c0 + ci] + tile[pi][ci];
  }
}

extern "C" void kernel_launch(void* const* d_in, const int* in_sizes, int n_in,
                              void* d_out, int out_size, void* d_ws, size_t ws_size,
                              hipStream_t stream) {
  (void)in_sizes; (void)n_in; (void)out_size;
  const float* x      = (const float*)d_in[0];
  const float* gamma  = (const float*)d_in[1];
  const float* beta   = (const float*)d_in[2];
  const float* q_w    = (const float*)d_in[3];
  const float* q_b    = (const float*)d_in[4];
  const float* k_w    = (const float*)d_in[5];
  const float* k_b    = (const float*)d_in[6];
  const float* v_w    = (const float*)d_in[7];
  const float* v_b    = (const float*)d_in[8];
  const float* proj_w = (const float*)d_in[9];
  const float* proj_b = (const float*)d_in[10];

  // workspace layout (bytes)
  const size_t OFF_WB    = 0;            // 2 MB: wq|wk|wv|wp bf16
  const size_t OFF_BIAS  = 2097152;      // 6 KB: qkv bias
  const size_t OFF_STATS = 2103296;      // 512 B
  const size_t OFF_PART  = 2103808;      // 16 KB
  const size_t OFF_HN    = 2121728;      // 32 MB (reused as vT)
  const size_t OFF_QKV   = 35676160;     // 96 MB: [32768][1536] bf16 (reused as projout fp32)
  const size_t OFF_SC    = 136339456;    // scores bf16: CH frames * 2 MB

  char* ws = (char*)d_ws;
  u16*    wb      = (u16*)(ws + OFF_WB);
  float*  qkvbias = (float*)(ws + OFF_BIAS);
  float2* stats   = (float2*)(ws + OFF_STATS);
  float2* part    = (float2*)(ws + OFF_PART);
  u16*    hn      = (u16*)(ws + OFF_HN);
  u16*    vT      = hn;                       // hn dead after QKV GEMM
  u16*    qkv     = (u16*)(ws + OFF_QKV);
  float*  projout = (float*)(ws + OFF_QKV);   // qkv dead after attention
  u16*    scores  = (u16*)(ws + OFF_SC);

  const int CH = (ws_size >= 237002752ULL) ? 32 : 8;  // frames per attention chunk
  u16* ob = (u16*)(ws + OFF_SC + (size_t)CH * 2097152);

  wconv<<<1024, 256, 0, stream>>>(q_w, k_w, v_w, proj_w, wb);
  bcat<<<6, 256, 0, stream>>>(q_b, k_b, v_b, qkvbias);
  gn_stats_a<<<2048, 256, 0, stream>>>(x, part);
  gn_stats_b<<<64, 64, 0, stream>>>(part, stats);
  gn_apply<<<dim3(16, 8, 32), 256, 0, stream>>>(x, gamma, beta, stats, hn);

  // fused QKV: M=32768, N=1536, K=512 -> qkv bf16 [32768][1536]
  gemm256<true, true><<<dim3(128, 6, 1), 512, 0, stream>>>(
      hn, 512, 0, wb, 512, 0, qkv, 1536, 0, qkvbias, 512);

  transpose_pc<<<dim3(16, 8, 32), 256, 0, stream>>>(qkv + 1024, 1536, vT);

  for (int ch = 0; ch < 32 / CH; ++ch) {
    long f0 = (long)ch * CH;
    // scores = q @ k^T (bf16 out): M=N=1024, K=512, batched over CH frames
    gemm256<true, false><<<dim3(4, 4, CH), 512, 0, stream>>>(
        qkv + f0 * 1572864, 1536, 1572864,
        qkv + 512 + f0 * 1572864, 1536, 1572864,
        scores, 1024, 1048576, nullptr, 512);
    softmax_rows_bf16<<<CH * 256, 256, 0, stream>>>(scores);
    // o = P @ vT^T : M=1024, N=512, K=1024
    gemm256<true, false><<<dim3(4, 2, CH), 512, 0, stream>>>(
        scores, 1024, 1048576,
        vT + f0 * 524288, 1024, 524288,
        ob + f0 * 524288, 512, 524288, nullptr, 1024);
  }

  // proj: M=32768, N=512, K=512 -> fp32
  gemm256<false, false><<<dim3(128, 2, 1), 512, 0, stream>>>(
      ob, 512, 0, wb + 786432, 512, 0, projout, 512, 0, nullptr, 512);
  final_write<<<dim3(16, 8, 32), 256, 0, stream>>>(projout, proj_b, x, (float*)d_out);
}

// Round 3
// 306.532 us; speedup vs baseline: 1.4160x; 1.0396x over previous
//
#include <hip/hip_runtime.h>

typedef unsigned short u16;
typedef __attribute__((ext_vector_type(8))) short bf16x8;
typedef __attribute__((ext_vector_type(4))) float f32x4;

#define DEV static __device__ __forceinline__

DEV u16 f2bf(float f) {
  union { float f; unsigned u; } x; x.f = f;
  return (u16)((x.u + 0x7FFFu + ((x.u >> 16) & 1u)) >> 16);
}
DEV float bf2f(u16 h) { union { unsigned u; float f; } x; x.u = ((unsigned)h) << 16; return x.f; }

DEV void gload16(const void* g, void* l) {
  __builtin_amdgcn_global_load_lds((const __attribute__((address_space(1))) void*)g,
                                   (__attribute__((address_space(3))) void*)l, 16, 0, 0);
}

// ---------------- GroupNorm stats (2-stage) ----------------
__global__ __launch_bounds__(256) void gn_stats_a(const float* __restrict__ x,
                                                  float2* __restrict__ part) {
  const int bg = blockIdx.x >> 5, slice = blockIdx.x & 31;
  const float* base = x + (long)bg * 262144 + slice * 8192;
  float s = 0.f, q = 0.f;
#pragma unroll
  for (int i = 0; i < 8; ++i) {
    float4 v = *(const float4*)(base + i * 1024 + threadIdx.x * 4);
    s += v.x + v.y + v.z + v.w;
    q += v.x * v.x + v.y * v.y + v.z * v.z + v.w * v.w;
  }
#pragma unroll
  for (int o = 32; o; o >>= 1) { s += __shfl_xor(s, o); q += __shfl_xor(q, o); }
  __shared__ float2 red[4];
  if ((threadIdx.x & 63) == 0) red[threadIdx.x >> 6] = make_float2(s, q);
  __syncthreads();
  if (threadIdx.x == 0) {
    float S = 0.f, Q = 0.f;
    for (int i = 0; i < 4; ++i) { S += red[i].x; Q += red[i].y; }
    part[blockIdx.x] = make_float2(S, Q);
  }
}

__global__ void gn_stats_b(const float2* __restrict__ part, float2* __restrict__ stats) {
  float s = 0.f, q = 0.f;
  if (threadIdx.x < 32) {
    float2 p = part[blockIdx.x * 32 + threadIdx.x];
    s = p.x; q = p.y;
  }
#pragma unroll
  for (int o = 32; o; o >>= 1) { s += __shfl_xor(s, o); q += __shfl_xor(q, o); }
  if (threadIdx.x == 0) {
    const float inv = 1.f / 262144.f;
    float mean = s * inv;
    float var = q * inv - mean * mean;
    stats[blockIdx.x] = make_float2(mean, rsqrtf(var + 1e-6f));
  }
}

// Normalize + transpose [b,c,t,p] -> hn[(b*16+t)*1024+p][c] bf16
__global__ __launch_bounds__(256) void gn_apply(const float* __restrict__ x,
                                                const float* __restrict__ gamma,
                                                const float* __restrict__ beta,
                                                const float2* __restrict__ stats,
                                                u16* __restrict__ hn) {
  __shared__ u16 tile[64][65];
  const int p0 = blockIdx.x * 64, c0 = blockIdx.y * 64, bt = blockIdx.z;
  const int b = bt >> 4, t = bt & 15, tid = threadIdx.x;
  const float* xb = x + (long)b * 8388608 + t * 1024;
#pragma unroll 4
  for (int r = 0; r < 16; ++r) {
    int ci = r * 4 + (tid >> 6), pi = tid & 63;
    int c = c0 + ci;
    float2 st = stats[b * 32 + (c >> 4)];
    float v = xb[(long)c * 16384 + p0 + pi];
    v = (v - st.x) * st.y * gamma[c] + beta[c];
    tile[ci][pi] = f2bf(v);
  }
  __syncthreads();
  u16* hb = hn + ((long)bt * 1024 + p0) * 512 + c0;
#pragma unroll 4
  for (int r = 0; r < 16; ++r) {
    int pi = r * 4 + (tid >> 6), ci = tid & 63;
    hb[(long)pi * 512 + ci] = tile[ci][pi];
  }
}

// fp32 -> bf16 weight convert: 4 matrices of 512*512 concatenated (q,k,v, proj)
__global__ __launch_bounds__(256) void wconv(const float* __restrict__ w0, const float* __restrict__ w1,
                                             const float* __restrict__ w2, const float* __restrict__ w3,
                                             u16* __restrict__ dst) {
  int e = (blockIdx.x * 256 + threadIdx.x) * 4;
  const float* src = w0;
  int which = e >> 18, off = e & 262143;
  if (which == 1) src = w1; else if (which == 2) src = w2; else if (which == 3) src = w3;
  float4 v = *(const float4*)(src + off);
  ushort4 o;
  o.x = f2bf(v.x); o.y = f2bf(v.y); o.z = f2bf(v.z); o.w = f2bf(v.w);
  *(ushort4*)(dst + e) = o;
}

__global__ void bcat(const float* __restrict__ qb, const float* __restrict__ kb,
                     const float* __restrict__ vb, float* __restrict__ dst) {
  int i = blockIdx.x * 256 + threadIdx.x;
  if (i < 512) dst[i] = qb[i];
  else if (i < 1024) dst[i] = kb[i - 512];
  else if (i < 1536) dst[i] = vb[i - 1024];
}

// v[bt][p][c] (row stride ldv) -> vT[bt][c][p]  (bf16)
__global__ __launch_bounds__(256) void transpose_pc(const u16* __restrict__ v, int ldv,
                                                    u16* __restrict__ vT) {
  __shared__ u16 tile[64][65];
  const int p0 = blockIdx.x * 64, c0 = blockIdx.y * 64;
  const long bt = blockIdx.z;
  const int tid = threadIdx.x;
  const u16* vb = v + bt * 1024 * (long)ldv;
#pragma unroll 4
  for (int r = 0; r < 16; ++r) {
    int pi = r * 4 + (tid >> 6), ci = tid & 63;
    tile[pi][ci] = vb[(long)(p0 + pi) * ldv + c0 + ci];
  }
  __syncthreads();
  u16* ob = vT + bt * 524288;
#pragma unroll 4
  for (int r = 0; r < 16; ++r) {
    int ci = r * 4 + (tid >> 6), pi = tid & 63;
    ob[(long)(c0 + ci) * 1024 + p0 + pi] = tile[pi][ci];
  }
}

// Row softmax over 1024 bf16 cols, in place. 4 rows/block (1 row per wave).
__global__ __launch_bounds__(256) void softmax_rows_bf16(u16* __restrict__ scores) {
  const int wave = threadIdx.x >> 6, lane = threadIdx.x & 63;
  const long row = (long)blockIdx.x * 4 + wave;
  u16* srow = scores + row * 1024;
  bf16x8 a0 = *(const bf16x8*)(srow + lane * 16);
  bf16x8 a1 = *(const bf16x8*)(srow + lane * 16 + 8);
  float v[16];
#pragma unroll
  for (int j = 0; j < 8; ++j) { v[j] = bf2f((u16)a0[j]); v[8 + j] = bf2f((u16)a1[j]); }
  float m = v[0];
#pragma unroll
  for (int j = 1; j < 16; ++j) m = fmaxf(m, v[j]);
#pragma unroll
  for (int o = 32; o; o >>= 1) m = fmaxf(m, __shfl_xor(m, o));
  const float sc = 0.044194173824159216f;  // 1/sqrt(512)
  float s = 0.f, e[16];
#pragma unroll
  for (int j = 0; j < 16; ++j) { e[j] = __expf((v[j] - m) * sc); s += e[j]; }
#pragma unroll
  for (int o = 32; o; o >>= 1) s += __shfl_xor(s, o);
  const float inv = 1.f / s;
  bf16x8 o0, o1;
#pragma unroll
  for (int j = 0; j < 8; ++j) {
    o0[j] = (short)f2bf(e[j] * inv);
    o1[j] = (short)f2bf(e[8 + j] * inv);
  }
  *(bf16x8*)(srow + lane * 16) = o0;
  *(bf16x8*)(srow + lane * 16 + 8) = o1;
}

// ---------------- NT GEMM, 256x256 tile, BK=64, 8-phase pipeline (m201-style) ------
// C[m,n] = sum_k A[m,k]*B[n,k] (+bias[n]).  8 waves (2M x 4N), wave tile 128x64.
// 2 LDS buffers x (A 256x64 + B 256x64) bf16 = 128 KB. 4 phases per K-tile:
//   p0: rd A(mi0-3,kk0)+B(kk0), stage A0(T+1) | p1: rd A(mi4-7,kk0), stage A1(T+1)
//   p2: rd A(mi0-3,kk1)+B(kk1), stage B1(T+1) | p3: rd A(mi4-7,kk1), stage B0(T+2)
// Each phase: reads | stage -> s_barrier -> lgkmcnt(0) -> 16 MFMA -> s_barrier.
// Every DMA target is disjoint from that phase's reads; overwrites land >=1 barrier
// after last read of old data. Counted vmcnt(2) once per tile at the boundary.
#define SYNC_MID() do { asm volatile("" ::: "memory"); __builtin_amdgcn_s_barrier(); \
  asm volatile("s_waitcnt lgkmcnt(0)" ::: "memory"); __builtin_amdgcn_sched_barrier(0); } while (0)
#define SYNC_END() do { asm volatile("" ::: "memory"); __builtin_amdgcn_s_barrier(); \
  asm volatile("" ::: "memory"); } while (0)

template <bool OUT_BF16, bool HAS_BIAS>
__global__ __launch_bounds__(512, 2) void gemm8p(
    const u16* __restrict__ A, int lda, long sA,
    const u16* __restrict__ B, int ldb, long sB,
    void* __restrict__ Cv, int ldc, long sC,
    const float* __restrict__ bias, int K) {
  __shared__ u16 sm[2 * 32768];  // buf b (bytes): A at b*65536, B at b*65536+32768
  const int tid = threadIdx.x;
  const int wid = tid >> 6, lane = tid & 63;
  const int wm = wid >> 2, wn = wid & 3;

  int bx = blockIdx.x, by = blockIdx.y;
  if (gridDim.z == 1 && (((int)gridDim.x * (int)gridDim.y) & 7) == 0) {
    int gy = gridDim.y;
    int d = by * gridDim.x + bx;            // HW dispatch order (x fastest)
    int per = ((int)gridDim.x * gy) >> 3;
    int w = (d & 7) * per + (d >> 3);       // chunk per XCD
    bx = w / gy; by = w % gy;               // consecutive w share bx (A-panel)
  }
  const long m0 = (long)bx * 256;
  const long n0 = (long)by * 256;
  A += (long)blockIdx.z * sA + m0 * lda;
  B += (long)blockIdx.z * sB + n0 * ldb;
  const int NT = K >> 6;

  f32x4 acc[8][4] = {};

  char* smc = (char*)sm;
  // which: 0=A rows0-127, 1=A rows128-255, 2=B rows0-127, 3=B rows128-255
  auto STAGE_HALF = [&](int kt, int which) {
    const char* src = (const char*)((which < 2) ? A : B);
    const long ldby = 2L * ((which < 2) ? lda : ldb);
    const int rowbase = (which & 1) * 128;
    char* dst = smc + (kt & 1) * 65536 + ((which < 2) ? 0 : 32768) + rowbase * 128;
    const char* gk = src + (long)kt * 128;
#pragma unroll
    for (int i = 0; i < 2; ++i) {
      int rl = i * 64 + (tid >> 3);
      int cb = (tid & 7) * 16;
      int scb = cb ^ ((rl & 7) << 4);
      gload16(gk + (long)(rowbase + rl) * ldby + scb, dst + rl * 128 + cb);
    }
  };

  const int lrow = lane & 15, kslot = (lane >> 4) * 16;
  auto RD_A = [&](int buf, int kk, int mh, bf16x8* af) {
#pragma unroll
    for (int mi = 0; mi < 4; ++mi) {
      int row = wm * 128 + (mh * 4 + mi) * 16 + lrow;
      int cb = (kk * 64 + kslot) ^ ((row & 7) << 4);
      af[mi] = *(const bf16x8*)(smc + buf * 65536 + row * 128 + cb);
    }
  };
  auto RD_B = [&](int buf, int kk, bf16x8* bf) {
#pragma unroll
    for (int ni = 0; ni < 4; ++ni) {
      int row = wn * 64 + ni * 16 + lrow;
      int cb = (kk * 64 + kslot) ^ ((row & 7) << 4);
      bf[ni] = *(const bf16x8*)(smc + buf * 65536 + 32768 + row * 128 + cb);
    }
  };

  // prologue: tile0 all 4 halves, then B0(1); wait all but last stage
  STAGE_HALF(0, 0); STAGE_HALF(0, 1); STAGE_HALF(0, 2); STAGE_HALF(0, 3);
  STAGE_HALF(1, 2);
  asm volatile("s_waitcnt vmcnt(2)" ::: "memory");
  SYNC_END();

  for (int T = 0; T < NT; ++T) {
    const int cur = T & 1;
    const bool s1 = (T + 1 < NT), s2 = (T + 2 < NT);
    bf16x8 af[4], bf[4];
    // ---- phase 0: kk0, mi 0-3 ----
    RD_B(cur, 0, bf);
    RD_A(cur, 0, 0, af);
    if (s1) STAGE_HALF(T + 1, 0);
    SYNC_MID();
    __builtin_amdgcn_s_setprio(1);
#pragma unroll
    for (int mi = 0; mi < 4; ++mi)
#pragma unroll
      for (int ni = 0; ni < 4; ++ni)
        acc[mi][ni] = __builtin_amdgcn_mfma_f32_16x16x32_bf16(af[mi], bf[ni], acc[mi][ni], 0, 0, 0);
    __builtin_amdgcn_s_setprio(0);
    SYNC_END();
    // ---- phase 1: kk0, mi 4-7 ----
    RD_A(cur, 0, 1, af);
    if (s1) STAGE_HALF(T + 1, 1);
    SYNC_MID();
    __builtin_amdgcn_s_setprio(1);
#pragma unroll
    for (int mi = 0; mi < 4; ++mi)
#pragma unroll
      for (int ni = 0; ni < 4; ++ni)
        acc[4 + mi][ni] = __builtin_amdgcn_mfma_f32_16x16x32_bf16(af[mi], bf[ni], acc[4 + mi][ni], 0, 0, 0);
    __builtin_amdgcn_s_setprio(0);
    SYNC_END();
    // ---- phase 2: kk1, mi 0-3 ----
    RD_B(cur, 1, bf);
    RD_A(cur, 1, 0, af);
    if (s1) STAGE_HALF(T + 1, 3);
    SYNC_MID();
    __builtin_amdgcn_s_setprio(1);
#pragma unroll
    for (int mi = 0; mi < 4; ++mi)
#pragma unroll
      for (int ni = 0; ni < 4; ++ni)
        acc[mi][ni] = __builtin_amdgcn_mfma_f32_16x16x32_bf16(af[mi], bf[ni], acc[mi][ni], 0, 0, 0);
    __builtin_amdgcn_s_setprio(0);
    SYNC_END();
    // ---- phase 3: kk1, mi 4-7 ----
    RD_A(cur, 1, 1, af);
    if (s2) STAGE_HALF(T + 2, 2);
    SYNC_MID();
    __builtin_amdgcn_s_setprio(1);
#pragma unroll
    for (int mi = 0; mi < 4; ++mi)
#pragma unroll
      for (int ni = 0; ni < 4; ++ni)
        acc[4 + mi][ni] = __builtin_amdgcn_mfma_f32_16x16x32_bf16(af[mi], bf[ni], acc[4 + mi][ni], 0, 0, 0);
    __builtin_amdgcn_s_setprio(0);
    if (s2) asm volatile("s_waitcnt vmcnt(2)" ::: "memory");
    else    asm volatile("s_waitcnt vmcnt(0)" ::: "memory");
    SYNC_END();
  }

  // C/D layout: col = lane&15, row = (lane>>4)*4 + j
  const int lc = lane & 15, lr = (lane >> 4) * 4;
  if (OUT_BF16) {
    u16* C = (u16*)Cv + (long)blockIdx.z * sC;
#pragma unroll
    for (int mi = 0; mi < 8; ++mi) {
      long r = m0 + wm * 128 + mi * 16 + lr;
#pragma unroll
      for (int ni = 0; ni < 4; ++ni) {
        long c = n0 + wn * 64 + ni * 16 + lc;
        float bv = HAS_BIAS ? bias[c] : 0.f;
#pragma unroll
        for (int j = 0; j < 4; ++j) C[(r + j) * ldc + c] = f2bf(acc[mi][ni][j] + bv);
      }
    }
  } else {
    float* C = (float*)Cv + (long)blockIdx.z * sC;
#pragma unroll
    for (int mi = 0; mi < 8; ++mi) {
      long r = m0 + wm * 128 + mi * 16 + lr;
#pragma unroll
      for (int ni = 0; ni < 4; ++ni) {
        long c = n0 + wn * 64 + ni * 16 + lc;
        float bv = HAS_BIAS ? bias[c] : 0.f;
#pragma unroll
        for (int j = 0; j < 4; ++j) C[(r + j) * ldc + c] = acc[mi][ni][j] + bv;
      }
    }
  }
}

// projout[m][c] (+proj_b) + x -> d_out in [b,c,t,p] layout
__global__ __launch_bounds__(256) void final_write(const float* __restrict__ projout,
                                                   const float* __restrict__ proj_b,
                                                   const float* __restrict__ x,
                                                   float* __restrict__ out) {
  __shared__ float tile[64][65];
  const int p0 = blockIdx.x * 64, c0 = blockIdx.y * 64, bt = blockIdx.z;
  const int b = bt >> 4, t = bt & 15, tid = threadIdx.x;
  const float* pr = projout + ((long)bt * 1024 + p0) * 512 + c0;
#pragma unroll 4
  for (int r = 0; r < 16; ++r) {
    int pi = r * 4 + (tid >> 6), ci = tid & 63;
    tile[pi][ci] = pr[(long)pi * 512 + ci];
  }
  __syncthreads();
  const long obase = (long)b * 8388608 + t * 1024;
#pragma unroll 4
  for (int r = 0; r < 16; ++r) {
    int ci = r * 4 + (tid >> 6), pi = tid & 63;
    long idx = obase + (long)(c0 + ci) * 16384 + p0 + pi;
    out[idx] = x[idx] + proj_b[c0 + ci] + tile[pi][ci];
  }
}

extern "C" void kernel_launch(void* const* d_in, const int* in_sizes, int n_in,
                              void* d_out, int out_size, void* d_ws, size_t ws_size,
                              hipStream_t stream) {
  (void)in_sizes; (void)n_in; (void)out_size;
  const float* x      = (const float*)d_in[0];
  const float* gamma  = (const float*)d_in[1];
  const float* beta   = (const float*)d_in[2];
  const float* q_w    = (const float*)d_in[3];
  const float* q_b    = (const float*)d_in[4];
  const float* k_w    = (const float*)d_in[5];
  const float* k_b    = (const float*)d_in[6];
  const float* v_w    = (const float*)d_in[7];
  const float* v_b    = (const float*)d_in[8];
  const float* proj_w = (const float*)d_in[9];
  const float* proj_b = (const float*)d_in[10];

  // workspace layout (bytes)
  const size_t OFF_WB    = 0;            // 2 MB: wq|wk|wv|wp bf16
  const size_t OFF_BIAS  = 2097152;      // 6 KB: qkv bias
  const size_t OFF_STATS = 2103296;      // 512 B
  const size_t OFF_PART  = 2103808;      // 16 KB
  const size_t OFF_HN    = 2121728;      // 32 MB (reused as vT)
  const size_t OFF_QKV   = 35676160;     // 96 MB: [32768][1536] bf16 (reused as projout fp32)
  const size_t OFF_SC    = 136339456;    // scores bf16: CH frames * 2 MB

  char* ws = (char*)d_ws;
  u16*    wb      = (u16*)(ws + OFF_WB);
  float*  qkvbias = (float*)(ws + OFF_BIAS);
  float2* stats   = (float2*)(ws + OFF_STATS);
  float2* part    = (float2*)(ws + OFF_PART);
  u16*    hn      = (u16*)(ws + OFF_HN);
  u16*    vT      = hn;                       // hn dead after QKV GEMM
  u16*    qkv     = (u16*)(ws + OFF_QKV);
  float*  projout = (float*)(ws + OFF_QKV);   // qkv dead after attention
  u16*    scores  = (u16*)(ws + OFF_SC);

  const int CH = (ws_size >= 237002752ULL) ? 32 : 8;  // frames per attention chunk
  u16* ob = (u16*)(ws + OFF_SC + (size_t)CH * 2097152);

  wconv<<<1024, 256, 0, stream>>>(q_w, k_w, v_w, proj_w, wb);
  bcat<<<6, 256, 0, stream>>>(q_b, k_b, v_b, qkvbias);
  gn_stats_a<<<2048, 256, 0, stream>>>(x, part);
  gn_stats_b<<<64, 64, 0, stream>>>(part, stats);
  gn_apply<<<dim3(16, 8, 32), 256, 0, stream>>>(x, gamma, beta, stats, hn);

  // fused QKV: M=32768, N=1536, K=512 -> qkv bf16 [32768][1536]
  gemm8p<true, true><<<dim3(128, 6, 1), 512, 0, stream>>>(
      hn, 512, 0, wb, 512, 0, qkv, 1536, 0, qkvbias, 512);

  transpose_pc<<<dim3(16, 8, 32), 256, 0, stream>>>(qkv + 1024, 1536, vT);

  for (int ch = 0; ch < 32 / CH; ++ch) {
    long f0 = (long)ch * CH;
    // scores = q @ k^T (bf16 out): M=N=1024, K=512, batched over CH frames
    gemm8p<true, false><<<dim3(4, 4, CH), 512, 0, stream>>>(
        qkv + f0 * 1572864, 1536, 1572864,
        qkv + 512 + f0 * 1572864, 1536, 1572864,
        scores, 1024, 1048576, nullptr, 512);
    softmax_rows_bf16<<<CH * 256, 256, 0, stream>>>(scores);
    // o = P @ vT^T : M=1024, N=512, K=1024
    gemm8p<true, false><<<dim3(4, 2, CH), 512, 0, stream>>>(
        scores, 1024, 1048576,
        vT + f0 * 524288, 1024, 524288,
        ob + f0 * 524288, 512, 524288, nullptr, 1024);
  }

  // proj: M=32768, N=512, K=512 -> fp32
  gemm8p<false, false><<<dim3(128, 2, 1), 512, 0, stream>>>(
      ob, 512, 0, wb + 786432, 512, 0, projout, 512, 0, nullptr, 512);
  final_write<<<dim3(16, 8, 32), 256, 0, stream>>>(projout, proj_b, x, (float*)d_out);
}